// Round 20
// baseline (87.839 us; speedup 1.0000x reference)
//
#include <hip/hip_runtime.h>

typedef _Float16 f16;
typedef __attribute__((ext_vector_type(8))) _Float16 f16x8;
typedef __attribute__((ext_vector_type(4))) _Float16 f16x4;
typedef __attribute__((ext_vector_type(4))) float f32x4;

#define NB 16
#define LSEQ 2048
#define DIM 64
#define KVB 64
#define QT 128              // queries per block: 4 waves x 2 frags x 16
#define NQT (LSEQ / QT)     // 16
#define NT (LSEQ / KVB)     // 32
#define LOG2E 1.44269504088896340736f

__device__ inline f16x4 pkcvt(const f32x4 x) {
    auto a = __builtin_amdgcn_cvt_pkrtz(x[0], x[1]);
    auto b = __builtin_amdgcn_cvt_pkrtz(x[2], x[3]);
    f16x4 t; t[0]=(f16)a[0]; t[1]=(f16)a[1]; t[2]=(f16)b[0]; t[3]=(f16)b[1];
    return t;
}

__device__ inline void gload16(const void* g, void* l) {
    __builtin_amdgcn_global_load_lds(
        (const __attribute__((address_space(1))) unsigned int*)g,
        (__attribute__((address_space(3))) unsigned int*)l, 16, 0, 0);
}

// K-row permutation: storage row p = 16kt+4hi+g holds physical key
// kappa(p) = 32*(kt&1) + 8*hi + 4*(kt>>1) + g  (bijective bit shuffle).
// Makes QK's per-lane P layout EQUAL to PV's A-operand layout -> no P exchange.
__device__ __host__ inline int kappa(int p) {
    int kt = p >> 4, hi = (p >> 2) & 3, g = p & 3;
    return ((kt & 1) << 5) + (hi << 3) + ((kt >> 1) << 2) + g;
}

// ---- fused pre-kernel: blocks 0..511 convert K (row-permuted), V (transposed) -> f16; 512.. sort ----
__global__ __launch_bounds__(256) void prep(
    const float* __restrict__ kg, const float* __restrict__ vg,
    const int* __restrict__ vlg,
    f16* __restrict__ k16, f16* __restrict__ v16, int* __restrict__ perm)
{
    const int tid = threadIdx.x;
    if (blockIdx.x < NB * NT) {
        const int b = blockIdx.x & 15, t = blockIdx.x >> 4;
        const int bt = b * NT + t;       // storage layout: [b][t]
        const float* kb_ = kg + ((size_t)b * LSEQ + t * KVB) * DIM;
        const float* vb_ = vg + ((size_t)b * LSEQ + t * KVB) * DIM;
        f16* kd = k16 + (size_t)bt * (KVB * DIM);
        f16* vd = v16 + (size_t)bt * (KVB * DIM);
#pragma unroll
        for (int it = 0; it < 4; ++it) {
            int cc = tid + it * 256;
            int row = cc >> 4, c4 = (cc & 15) * 4;       // row = storage row p
            f32x4 x = *(const f32x4*)(kb_ + kappa(row) * DIM + c4);
            *(f16x4*)(kd + row * 64 + (c4 ^ ((row & 7) * 8))) = pkcvt(x);
        }
        int kb4 = tid & 15, dvb = tid >> 4;
        f32x4 rr[4];
#pragma unroll
        for (int i = 0; i < 4; ++i)
            rr[i] = *(const f32x4*)(vb_ + (size_t)(kb4 * 4 + i) * DIM + dvb * 4);
#pragma unroll
        for (int j = 0; j < 4; ++j) {
            int dv = dvb * 4 + j;
            f32x4 col = {rr[0][j], rr[1][j], rr[2][j], rr[3][j]};
            *(f16x4*)(vd + dv * 64 + ((kb4 * 4) ^ ((dv & 7) * 8))) = pkcvt(col);
        }
    } else {
        const int b = blockIdx.x - NB * NT;
        __shared__ int hist[NT + 1];
        __shared__ int base[NT + 1];
        if (tid <= NT) hist[tid] = 0;
        __syncthreads();
        for (int q = tid; q < LSEQ; q += 256) {
            int vl = vlg[b * LSEQ + q];
            int t = (vl == 0) ? NT : ((vl + KVB - 1) >> 6);
            atomicAdd(&hist[t], 1);
        }
        __syncthreads();
        if (tid == 0) {
            int acc = 0;
            for (int t = NT; t >= 0; --t) { base[t] = acc; acc += hist[t]; }
        }
        __syncthreads();
        for (int q = tid; q < LSEQ; q += 256) {
            int vl = vlg[b * LSEQ + q];
            int t = (vl == 0) ? NT : ((vl + KVB - 1) >> 6);
            int pos = atomicAdd(&base[t], 1);
            perm[b * LSEQ + pos] = q;
        }
    }
}

// ---- main attention: LDS dbuf + gload_lds; kappa in-lane P; 2-phase tile body shares K/V reads ----
// bid = qt*(NB*S) + s*NB + b  (heavy qt first; bid%8 == b%8 -> XCD L2 locality)
__global__ __launch_bounds__(256, 4) void attn_fwd(
    const float* __restrict__ qg, const int* __restrict__ vlg,
    const f16* __restrict__ k16, const f16* __restrict__ v16,
    float* __restrict__ outg, const int* __restrict__ perm,
    f16* __restrict__ opart, float* __restrict__ mlg, int S)
{
    __shared__ alignas(16) f16 kbuf[2][KVB * 64];   // 8KB each, swizzled K tile (kappa-permuted rows)
    __shared__ alignas(16) f16 vbuf[2][DIM * 64];   // 8KB each, swizzled V^T tile
    __shared__ int wmax[4];

    const int tid  = threadIdx.x;
    const int wid  = tid >> 6;
    const int lane = tid & 63;
    const int r    = lane & 15;
    const int hi   = lane >> 4;

    const int bid = blockIdx.x;
    const int nbs = NB * S;
    const int qt  = bid / nbs;
    const int rem = bid - qt * nbs;
    const int s   = rem >> 4;           // split
    const int b   = rem & 15;           // batch -> XCD = b%8
    const int qw  = qt * QT + wid * 16;

    const int qidxA = perm[b * LSEQ + qw + r];
    const int qidxB = perm[b * LSEQ + qw + 64 + r];
    const int vlA   = vlg[b * LSEQ + qidxA];
    const int vlB   = vlg[b * LSEQ + qidxB];

    int tq = max((vlA == 0) ? NT : ((vlA + KVB - 1) >> 6),
                 (vlB == 0) ? NT : ((vlB + KVB - 1) >> 6));
    tq = max(tq, __shfl_xor(tq, 1));
    tq = max(tq, __shfl_xor(tq, 2));
    tq = max(tq, __shfl_xor(tq, 4));
    tq = max(tq, __shfl_xor(tq, 8));
    if (lane == 0) wmax[wid] = tq;
    __syncthreads();
    const int maxt = max(max(wmax[0], wmax[1]), max(wmax[2], wmax[3]));

    auto rmin = [&](int v) {
        v = min(v, __shfl_xor(v, 1));
        v = min(v, __shfl_xor(v, 2));
        v = min(v, __shfl_xor(v, 4));
        v = min(v, __shfl_xor(v, 8));
        return v;
    };
    const int vminA = rmin(vlA);
    const int vminB = rmin(vlB);

    auto load_q = [&](int qidx, f16x8* qf) {
        const float* qrow = qg + ((size_t)(b * LSEQ + qidx)) * DIM;
#pragma unroll
        for (int ks = 0; ks < 2; ++ks) {
            f32x4 x = *(const f32x4*)(qrow + ks * 32 + hi * 8);
            f32x4 y = *(const f32x4*)(qrow + ks * 32 + hi * 8 + 4);
            f32x4 xs = {x[0]*LOG2E, x[1]*LOG2E, x[2]*LOG2E, x[3]*LOG2E};
            f32x4 ys = {y[0]*LOG2E, y[1]*LOG2E, y[2]*LOG2E, y[3]*LOG2E};
            f16x4 lo = pkcvt(xs), hh = pkcvt(ys);
            f16x8 t;
            t[0]=lo[0]; t[1]=lo[1]; t[2]=lo[2]; t[3]=lo[3];
            t[4]=hh[0]; t[5]=hh[1]; t[6]=hh[2]; t[7]=hh[3];
            qf[ks] = t;
        }
    };
    f16x8 qfA[2], qfB[2];
    load_q(qidxA, qfA);
    load_q(qidxB, qfB);

    float mA = -INFINITY, mB = -INFINITY;
    float lA = 0.0f, lB = 0.0f;
    f32x4 oA[4], oB[4];
#pragma unroll
    for (int dt = 0; dt < 4; ++dt) { oA[dt] = f32x4{0,0,0,0}; oB[dt] = f32x4{0,0,0,0}; }

    const f16* kt_base = k16 + (size_t)b * (NT * KVB * DIM);
    const f16* vt_base = v16 + (size_t)b * (NT * KVB * DIM);
    const int swz = (r & 7) * 8;

    auto stage = [&](int bi, int t) {
        const char* ks = (const char*)(kt_base + (size_t)t * 4096);
        const char* vs = (const char*)(vt_base + (size_t)t * 4096);
        char* kd = (char*)&kbuf[bi][0];
        char* vd = (char*)&vbuf[bi][0];
        gload16(ks + tid * 16,        kd + tid * 16);
        gload16(ks + 4096 + tid * 16, kd + 4096 + tid * 16);
        gload16(vs + tid * 16,        vd + tid * 16);
        gload16(vs + 4096 + tid * 16, vd + 4096 + tid * 16);
    };

    // QK phase: register K fragments feed BOTH query frags
    auto do_qk = [&](const f16x8* kf, const f16x8* qf, f32x4* st) {
        __builtin_amdgcn_s_setprio(1);
#pragma unroll
        for (int kt = 0; kt < 4; ++kt) {
            f32x4 acc = f32x4{0,0,0,0};
#pragma unroll
            for (int ks = 0; ks < 2; ++ks)
                acc = __builtin_amdgcn_mfma_f32_16x16x32_f16(kf[kt * 2 + ks], qf[ks], acc, 0, 0, 0);
            st[kt] = acc;
        }
        __builtin_amdgcn_s_setprio(0);
    };

    // softmax phase: mask (kappa keys), defer-max, produce in-lane pa
    auto do_sm = [&](f32x4* st, int vl, int vmin, float& m_run, float& l_run,
                     f32x4* o, int kv0, f16x8* pa) {
        float lanemax = -INFINITY;
        if (kv0 + KVB > vmin) {
#pragma unroll
            for (int kt = 0; kt < 4; ++kt)
#pragma unroll
                for (int g = 0; g < 4; ++g) {
                    int key = kv0 + ((kt & 1) << 5) + (hi << 3) + ((kt >> 1) << 2) + g;
                    float sv = (key < vl) ? st[kt][g] : -1e9f;
                    st[kt][g] = sv;
                    lanemax = fmaxf(lanemax, sv);
                }
        } else {
#pragma unroll
            for (int kt = 0; kt < 4; ++kt)
#pragma unroll
                for (int g = 0; g < 4; ++g)
                    lanemax = fmaxf(lanemax, st[kt][g]);
        }

        if (__any(lanemax > m_run + 8.0f)) {   // defer-max (T13)
            float tmax = lanemax;
            tmax = fmaxf(tmax, __shfl_xor(tmax, 16));
            tmax = fmaxf(tmax, __shfl_xor(tmax, 32));
            float m_new = fmaxf(m_run, tmax);
            float scale = exp2f(m_run - m_new);
            l_run *= scale;
            m_run = m_new;
#pragma unroll
            for (int g = 0; g < 4; ++g) {
                float sc = __shfl(scale, hi * 4 + g);
#pragma unroll
                for (int dt = 0; dt < 4; ++dt) o[dt][g] *= sc;
            }
        }

#pragma unroll
        for (int kt = 0; kt < 4; ++kt)
#pragma unroll
            for (int g = 0; g < 4; ++g) {
                float p = exp2f(st[kt][g] - m_run);
                l_run += p;
                pa[kt & 1][((kt >> 1) << 2) + g] = (f16)p;
            }
    };

    auto do_pv = [&](const f16x8* pa, const f16x8* vf, f32x4* o) {
        __builtin_amdgcn_s_setprio(1);
#pragma unroll
        for (int ks = 0; ks < 2; ++ks)
#pragma unroll
            for (int dt = 0; dt < 4; ++dt)
                o[dt] = __builtin_amdgcn_mfma_f32_16x16x32_f16(pa[ks], vf[dt * 2 + ks], o[dt], 0, 0, 0);
        __builtin_amdgcn_s_setprio(0);
    };

    if (s < maxt) stage(0, s);
    int c = 0;
    for (int tt = s; tt < maxt; tt += S) {
        __syncthreads();   // implicit vmcnt(0): buf[c] staged; all waves done with buf[c^1]
        if (tt + S < maxt) stage(c ^ 1, tt + S);
        const int kv0 = tt * KVB;

        // ---- phase 1: K fragments once, QK for both frags (kf dies after) ----
        f32x4 stA[4], stB[4];
        {
            f16x8 kf[8];
#pragma unroll
            for (int kt = 0; kt < 4; ++kt)
#pragma unroll
                for (int ks = 0; ks < 2; ++ks)
                    kf[kt * 2 + ks] = *(const f16x8*)(&kbuf[c][(kt * 16 + r) * 64 + ((ks * 32 + hi * 8) ^ swz)]);
            do_qk(kf, qfA, stA);
            do_qk(kf, qfB, stB);
        }

        // ---- phase 2: V fragments once, softmax+PV for both frags ----
        {
            f16x8 vf[8];
#pragma unroll
            for (int kt = 0; kt < 4; ++kt)
#pragma unroll
                for (int ks = 0; ks < 2; ++ks)
                    vf[kt * 2 + ks] = *(const f16x8*)(&vbuf[c][(kt * 16 + r) * 64 + ((ks * 32 + hi * 8) ^ swz)]);
            f16x8 pa[2];
            do_sm(stA, vlA, vminA, mA, lA, oA, kv0, pa);
            do_pv(pa, vf, oA);
            do_sm(stB, vlB, vminB, mB, lB, oB, kv0, pa);
            do_pv(pa, vf, oB);
        }
        c ^= 1;
    }

    // ---- epilogue ----
    auto epi = [&](float m_run, float l_run, f32x4* o, int qidx) {
        l_run += __shfl_xor(l_run, 16);
        l_run += __shfl_xor(l_run, 32);
        if (S == 1) {
            float inv = 1.0f / l_run;
#pragma unroll
            for (int g = 0; g < 4; ++g) {
                float iv = __shfl(inv, hi * 4 + g);
                int   qo = __shfl(qidx, hi * 4 + g);
                float* ob = outg + ((size_t)(b * LSEQ + qo)) * DIM;
#pragma unroll
                for (int dt = 0; dt < 4; ++dt)
                    ob[dt * 16 + r] = o[dt][g] * iv;
            }
        } else {
            f16* obase = opart + ((size_t)s * NB * LSEQ + (size_t)b * LSEQ) * DIM;
#pragma unroll
            for (int g = 0; g < 4; ++g) {
                int qo = __shfl(qidx, hi * 4 + g);
                f16* ob = obase + (size_t)qo * DIM;
#pragma unroll
                for (int dt = 0; dt < 4; ++dt)
                    ob[dt * 16 + r] = (f16)o[dt][g];
            }
            if (hi == 0) {
                size_t mi = ((size_t)s * NB * LSEQ + (size_t)b * LSEQ + qidx) * 2;
                mlg[mi]     = m_run;
                mlg[mi + 1] = l_run;
            }
        }
    };
    epi(mA, lA, oA, qidxA);
    epi(mB, lB, oB, qidxB);
}

// ---- merge kernel: combine S online-softmax partials exactly (opart in f16) ----
__global__ void merge_k(const f16* __restrict__ opart, const float* __restrict__ mlg,
                        float* __restrict__ outg, int S)
{
    const int gt = blockIdx.x * 256 + threadIdx.x;
    const size_t base = (size_t)gt * 4;
    const size_t qg = base >> 6;
    float M = -INFINITY;
    for (int s = 0; s < S; ++s)
        M = fmaxf(M, mlg[((size_t)s * NB * LSEQ + qg) * 2]);
    float den = 0.f;
    f32x4 acc = {0.f, 0.f, 0.f, 0.f};
    for (int s = 0; s < S; ++s) {
        size_t mi = ((size_t)s * NB * LSEQ + qg) * 2;
        float w = exp2f(mlg[mi] - M);   // empty/fully-masked splits -> w=0
        den += w * mlg[mi + 1];
        f16x4 ov = *(const f16x4*)(opart + (size_t)s * (NB * LSEQ * DIM) + base);
        acc[0] += w * (float)ov[0]; acc[1] += w * (float)ov[1];
        acc[2] += w * (float)ov[2]; acc[3] += w * (float)ov[3];
    }
    float inv = 1.0f / den;
    f32x4 res = {acc[0]*inv, acc[1]*inv, acc[2]*inv, acc[3]*inv};
    *(f32x4*)(outg + base) = res;
}

extern "C" void kernel_launch(void* const* d_in, const int* in_sizes, int n_in,
                              void* d_out, int out_size, void* d_ws, size_t ws_size,
                              hipStream_t stream) {
    const float* q  = (const float*)d_in[0];
    const float* k  = (const float*)d_in[1];
    const float* v  = (const float*)d_in[2];
    const int*   vl = (const int*)d_in[3];
    float* out = (float*)d_out;

    const size_t perm_b = (size_t)NB * LSEQ * sizeof(int);          // 128 KB
    const size_t kv_b   = (size_t)NB * LSEQ * DIM * sizeof(f16);    // 4 MB each
    auto need = [&](int S) {
        return perm_b + 2 * kv_b
             + (size_t)S * NB * LSEQ * 2 * sizeof(float)
             + (size_t)S * NB * LSEQ * DIM * sizeof(f16);
    };
    int S;
    if      (ws_size >= need(4)) S = 4;
    else if (ws_size >= need(2)) S = 2;
    else                         S = 1;

    int*   perm  = (int*)d_ws;
    f16*   k16   = (f16*)((char*)d_ws + perm_b);
    f16*   v16   = (f16*)((char*)d_ws + perm_b + kv_b);
    float* mlg   = (float*)((char*)d_ws + perm_b + 2 * kv_b);
    f16*   opart = (f16*)((char*)d_ws + perm_b + 2 * kv_b
                          + (size_t)S * NB * LSEQ * 2 * sizeof(float));

    prep<<<NB * NT + NB, 256, 0, stream>>>(k, v, vl, k16, v16, perm);

    attn_fwd<<<dim3(NQT * NB * S), dim3(256), 0, stream>>>(
        q, vl, k16, v16, out, perm, opart, mlg, S);

    if (S > 1) {
        const int mthreads = NB * LSEQ * DIM / 4;
        merge_k<<<dim3(mthreads / 256), dim3(256), 0, stream>>>(opart, mlg, out, S);
    }
}

// Round 21
// 45.994 us; speedup vs baseline: 1.9098x; 1.9098x over previous
//
#include <hip/hip_runtime.h>

typedef _Float16 f16;
typedef __attribute__((ext_vector_type(8))) _Float16 f16x8;
typedef __attribute__((ext_vector_type(4))) _Float16 f16x4;
typedef __attribute__((ext_vector_type(4))) float f32x4;

#define NB 16
#define LSEQ 2048
#define DIM 64
#define KVB 64
#define QT 128              // queries per block: 4 waves x 2 frags x 16
#define NQT (LSEQ / QT)     // 16
#define NT (LSEQ / KVB)     // 32
#define LOG2E 1.44269504088896340736f

__device__ inline f16x4 pkcvt(const f32x4 x) {
    auto a = __builtin_amdgcn_cvt_pkrtz(x[0], x[1]);
    auto b = __builtin_amdgcn_cvt_pkrtz(x[2], x[3]);
    f16x4 t; t[0]=(f16)a[0]; t[1]=(f16)a[1]; t[2]=(f16)b[0]; t[3]=(f16)b[1];
    return t;
}

__device__ inline void gload16(const void* g, void* l) {
    __builtin_amdgcn_global_load_lds(
        (const __attribute__((address_space(1))) unsigned int*)g,
        (__attribute__((address_space(3))) unsigned int*)l, 16, 0, 0);
}

// K-row permutation: storage row p = 16kt+4hi+g holds physical key
// kappa(p) = 32*(kt&1) + 8*hi + 4*(kt>>1) + g  (bijective bit shuffle).
// Makes QK's per-lane P layout EQUAL to PV's A-operand layout -> no P exchange.
__device__ __host__ inline int kappa(int p) {
    int kt = p >> 4, hi = (p >> 2) & 3, g = p & 3;
    return ((kt & 1) << 5) + (hi << 3) + ((kt >> 1) << 2) + g;
}

// ---- fused pre-kernel: blocks 0..511 convert K (row-permuted), V (transposed) -> f16; 512.. sort ----
__global__ __launch_bounds__(256) void prep(
    const float* __restrict__ kg, const float* __restrict__ vg,
    const int* __restrict__ vlg,
    f16* __restrict__ k16, f16* __restrict__ v16, int* __restrict__ perm)
{
    const int tid = threadIdx.x;
    if (blockIdx.x < NB * NT) {
        const int b = blockIdx.x & 15, t = blockIdx.x >> 4;
        const int bt = b * NT + t;       // storage layout: [b][t]
        const float* kb_ = kg + ((size_t)b * LSEQ + t * KVB) * DIM;
        const float* vb_ = vg + ((size_t)b * LSEQ + t * KVB) * DIM;
        f16* kd = k16 + (size_t)bt * (KVB * DIM);
        f16* vd = v16 + (size_t)bt * (KVB * DIM);
#pragma unroll
        for (int it = 0; it < 4; ++it) {
            int cc = tid + it * 256;
            int row = cc >> 4, c4 = (cc & 15) * 4;       // row = storage row p
            f32x4 x = *(const f32x4*)(kb_ + kappa(row) * DIM + c4);
            *(f16x4*)(kd + row * 64 + (c4 ^ ((row & 7) * 8))) = pkcvt(x);
        }
        int kb4 = tid & 15, dvb = tid >> 4;
        f32x4 rr[4];
#pragma unroll
        for (int i = 0; i < 4; ++i)
            rr[i] = *(const f32x4*)(vb_ + (size_t)(kb4 * 4 + i) * DIM + dvb * 4);
#pragma unroll
        for (int j = 0; j < 4; ++j) {
            int dv = dvb * 4 + j;
            f32x4 col = {rr[0][j], rr[1][j], rr[2][j], rr[3][j]};
            *(f16x4*)(vd + dv * 64 + ((kb4 * 4) ^ ((dv & 7) * 8))) = pkcvt(col);
        }
    } else {
        const int b = blockIdx.x - NB * NT;
        __shared__ int hist[NT + 1];
        __shared__ int base[NT + 1];
        if (tid <= NT) hist[tid] = 0;
        __syncthreads();
        for (int q = tid; q < LSEQ; q += 256) {
            int vl = vlg[b * LSEQ + q];
            int t = (vl == 0) ? NT : ((vl + KVB - 1) >> 6);
            atomicAdd(&hist[t], 1);
        }
        __syncthreads();
        if (tid == 0) {
            int acc = 0;
            for (int t = NT; t >= 0; --t) { base[t] = acc; acc += hist[t]; }
        }
        __syncthreads();
        for (int q = tid; q < LSEQ; q += 256) {
            int vl = vlg[b * LSEQ + q];
            int t = (vl == 0) ? NT : ((vl + KVB - 1) >> 6);
            int pos = atomicAdd(&base[t], 1);
            perm[b * LSEQ + pos] = q;
        }
    }
}

// ---- main attention: LDS dbuf + gload_lds; kappa in-lane P; kt/dt-granular shared K/V reads ----
// bid = qt*(NB*S) + s*NB + b  (heavy qt first; bid%8 == b%8 -> XCD L2 locality)
__global__ __launch_bounds__(256, 4) void attn_fwd(
    const float* __restrict__ qg, const int* __restrict__ vlg,
    const f16* __restrict__ k16, const f16* __restrict__ v16,
    float* __restrict__ outg, const int* __restrict__ perm,
    f16* __restrict__ opart, float* __restrict__ mlg, int S)
{
    __shared__ alignas(16) f16 kbuf[2][KVB * 64];   // 8KB each, swizzled K tile (kappa-permuted rows)
    __shared__ alignas(16) f16 vbuf[2][DIM * 64];   // 8KB each, swizzled V^T tile
    __shared__ int wmax[4];

    const int tid  = threadIdx.x;
    const int wid  = tid >> 6;
    const int lane = tid & 63;
    const int r    = lane & 15;
    const int hi   = lane >> 4;

    const int bid = blockIdx.x;
    const int nbs = NB * S;
    const int qt  = bid / nbs;
    const int rem = bid - qt * nbs;
    const int s   = rem >> 4;           // split
    const int b   = rem & 15;           // batch -> XCD = b%8
    const int qw  = qt * QT + wid * 16;

    const int qidxA = perm[b * LSEQ + qw + r];
    const int qidxB = perm[b * LSEQ + qw + 64 + r];
    const int vlA   = vlg[b * LSEQ + qidxA];
    const int vlB   = vlg[b * LSEQ + qidxB];

    int tq = max((vlA == 0) ? NT : ((vlA + KVB - 1) >> 6),
                 (vlB == 0) ? NT : ((vlB + KVB - 1) >> 6));
    tq = max(tq, __shfl_xor(tq, 1));
    tq = max(tq, __shfl_xor(tq, 2));
    tq = max(tq, __shfl_xor(tq, 4));
    tq = max(tq, __shfl_xor(tq, 8));
    if (lane == 0) wmax[wid] = tq;
    __syncthreads();
    const int maxt = max(max(wmax[0], wmax[1]), max(wmax[2], wmax[3]));

    auto rmin = [&](int v) {
        v = min(v, __shfl_xor(v, 1));
        v = min(v, __shfl_xor(v, 2));
        v = min(v, __shfl_xor(v, 4));
        v = min(v, __shfl_xor(v, 8));
        return v;
    };
    const int vminA = rmin(vlA);
    const int vminB = rmin(vlB);

    auto load_q = [&](int qidx, f16x8* qf) {
        const float* qrow = qg + ((size_t)(b * LSEQ + qidx)) * DIM;
#pragma unroll
        for (int ks = 0; ks < 2; ++ks) {
            f32x4 x = *(const f32x4*)(qrow + ks * 32 + hi * 8);
            f32x4 y = *(const f32x4*)(qrow + ks * 32 + hi * 8 + 4);
            f32x4 xs = {x[0]*LOG2E, x[1]*LOG2E, x[2]*LOG2E, x[3]*LOG2E};
            f32x4 ys = {y[0]*LOG2E, y[1]*LOG2E, y[2]*LOG2E, y[3]*LOG2E};
            f16x4 lo = pkcvt(xs), hh = pkcvt(ys);
            f16x8 t;
            t[0]=lo[0]; t[1]=lo[1]; t[2]=lo[2]; t[3]=lo[3];
            t[4]=hh[0]; t[5]=hh[1]; t[6]=hh[2]; t[7]=hh[3];
            qf[ks] = t;
        }
    };
    f16x8 qfA[2], qfB[2];
    load_q(qidxA, qfA);
    load_q(qidxB, qfB);

    float mA = -INFINITY, mB = -INFINITY;
    float lA = 0.0f, lB = 0.0f;
    f32x4 oA[4], oB[4];
#pragma unroll
    for (int dt = 0; dt < 4; ++dt) { oA[dt] = f32x4{0,0,0,0}; oB[dt] = f32x4{0,0,0,0}; }

    const f16* kt_base = k16 + (size_t)b * (NT * KVB * DIM);
    const f16* vt_base = v16 + (size_t)b * (NT * KVB * DIM);
    const int swz = (r & 7) * 8;

    auto stage = [&](int bi, int t) {
        const char* ks = (const char*)(kt_base + (size_t)t * 4096);
        const char* vs = (const char*)(vt_base + (size_t)t * 4096);
        char* kd = (char*)&kbuf[bi][0];
        char* vd = (char*)&vbuf[bi][0];
        gload16(ks + tid * 16,        kd + tid * 16);
        gload16(ks + 4096 + tid * 16, kd + 4096 + tid * 16);
        gload16(vs + tid * 16,        vd + tid * 16);
        gload16(vs + 4096 + tid * 16, vd + 4096 + tid * 16);
    };

    // softmax: mask (kappa keys), defer-max, produce in-lane pa (st dies here)
    auto do_sm = [&](f32x4* st, int vl, int vmin, float& m_run, float& l_run,
                     f32x4* o, int kv0, f16x8* pa) {
        float lanemax = -INFINITY;
        if (kv0 + KVB > vmin) {
#pragma unroll
            for (int kt = 0; kt < 4; ++kt)
#pragma unroll
                for (int g = 0; g < 4; ++g) {
                    int key = kv0 + ((kt & 1) << 5) + (hi << 3) + ((kt >> 1) << 2) + g;
                    float sv = (key < vl) ? st[kt][g] : -1e9f;
                    st[kt][g] = sv;
                    lanemax = fmaxf(lanemax, sv);
                }
        } else {
#pragma unroll
            for (int kt = 0; kt < 4; ++kt)
#pragma unroll
                for (int g = 0; g < 4; ++g)
                    lanemax = fmaxf(lanemax, st[kt][g]);
        }

        if (__any(lanemax > m_run + 8.0f)) {   // defer-max (T13)
            float tmax = lanemax;
            tmax = fmaxf(tmax, __shfl_xor(tmax, 16));
            tmax = fmaxf(tmax, __shfl_xor(tmax, 32));
            float m_new = fmaxf(m_run, tmax);
            float scale = exp2f(m_run - m_new);
            l_run *= scale;
            m_run = m_new;
#pragma unroll
            for (int g = 0; g < 4; ++g) {
                float sc = __shfl(scale, hi * 4 + g);
#pragma unroll
                for (int dt = 0; dt < 4; ++dt) o[dt][g] *= sc;
            }
        }

#pragma unroll
        for (int kt = 0; kt < 4; ++kt)
#pragma unroll
            for (int g = 0; g < 4; ++g) {
                float p = exp2f(st[kt][g] - m_run);
                l_run += p;
                pa[kt & 1][((kt >> 1) << 2) + g] = (f16)p;
            }
    };

    if (s < maxt) stage(0, s);
    int c = 0;
    for (int tt = s; tt < maxt; tt += S) {
        __syncthreads();   // implicit vmcnt(0): buf[c] staged; all waves done with buf[c^1]
        if (tt + S < maxt) stage(c ^ 1, tt + S);
        const int kv0 = tt * KVB;

        // ---- phase 1: per-kt K loads feed BOTH frags' QK (kf transient) ----
        f32x4 stA[4], stB[4];
        __builtin_amdgcn_s_setprio(1);
#pragma unroll
        for (int kt = 0; kt < 4; ++kt) {
            f16x8 kf0 = *(const f16x8*)(&kbuf[c][(kt * 16 + r) * 64 + ((0 * 32 + hi * 8) ^ swz)]);
            f16x8 kf1 = *(const f16x8*)(&kbuf[c][(kt * 16 + r) * 64 + ((1 * 32 + hi * 8) ^ swz)]);
            f32x4 a = __builtin_amdgcn_mfma_f32_16x16x32_f16(kf0, qfA[0], f32x4{0,0,0,0}, 0, 0, 0);
            stA[kt] = __builtin_amdgcn_mfma_f32_16x16x32_f16(kf1, qfA[1], a, 0, 0, 0);
            f32x4 bb = __builtin_amdgcn_mfma_f32_16x16x32_f16(kf0, qfB[0], f32x4{0,0,0,0}, 0, 0, 0);
            stB[kt] = __builtin_amdgcn_mfma_f32_16x16x32_f16(kf1, qfB[1], bb, 0, 0, 0);
        }
        __builtin_amdgcn_s_setprio(0);

        // ---- softmax both frags (st dies into pa) ----
        f16x8 paA[2], paB[2];
        do_sm(stA, vlA, vminA, mA, lA, oA, kv0, paA);
        do_sm(stB, vlB, vminB, mB, lB, oB, kv0, paB);

        // ---- phase 2: per-(dt,ks) V loads feed BOTH frags' PV (vf transient) ----
        __builtin_amdgcn_s_setprio(1);
#pragma unroll
        for (int dt = 0; dt < 4; ++dt)
#pragma unroll
            for (int ks = 0; ks < 2; ++ks) {
                f16x8 vf = *(const f16x8*)(&vbuf[c][(dt * 16 + r) * 64 + ((ks * 32 + hi * 8) ^ swz)]);
                oA[dt] = __builtin_amdgcn_mfma_f32_16x16x32_f16(paA[ks], vf, oA[dt], 0, 0, 0);
                oB[dt] = __builtin_amdgcn_mfma_f32_16x16x32_f16(paB[ks], vf, oB[dt], 0, 0, 0);
            }
        __builtin_amdgcn_s_setprio(0);
        c ^= 1;
    }

    // ---- epilogue ----
    auto epi = [&](float m_run, float l_run, f32x4* o, int qidx) {
        l_run += __shfl_xor(l_run, 16);
        l_run += __shfl_xor(l_run, 32);
        if (S == 1) {
            float inv = 1.0f / l_run;
#pragma unroll
            for (int g = 0; g < 4; ++g) {
                float iv = __shfl(inv, hi * 4 + g);
                int   qo = __shfl(qidx, hi * 4 + g);
                float* ob = outg + ((size_t)(b * LSEQ + qo)) * DIM;
#pragma unroll
                for (int dt = 0; dt < 4; ++dt)
                    ob[dt * 16 + r] = o[dt][g] * iv;
            }
        } else {
            f16* obase = opart + ((size_t)s * NB * LSEQ + (size_t)b * LSEQ) * DIM;
#pragma unroll
            for (int g = 0; g < 4; ++g) {
                int qo = __shfl(qidx, hi * 4 + g);
                f16* ob = obase + (size_t)qo * DIM;
#pragma unroll
                for (int dt = 0; dt < 4; ++dt)
                    ob[dt * 16 + r] = (f16)o[dt][g];
            }
            if (hi == 0) {
                size_t mi = ((size_t)s * NB * LSEQ + (size_t)b * LSEQ + qidx) * 2;
                mlg[mi]     = m_run;
                mlg[mi + 1] = l_run;
            }
        }
    };
    epi(mA, lA, oA, qidxA);
    epi(mB, lB, oB, qidxB);
}

// ---- merge kernel: combine S online-softmax partials exactly (opart in f16) ----
__global__ void merge_k(const f16* __restrict__ opart, const float* __restrict__ mlg,
                        float* __restrict__ outg, int S)
{
    const int gt = blockIdx.x * 256 + threadIdx.x;
    const size_t base = (size_t)gt * 4;
    const size_t qg = base >> 6;
    float M = -INFINITY;
    for (int s = 0; s < S; ++s)
        M = fmaxf(M, mlg[((size_t)s * NB * LSEQ + qg) * 2]);
    float den = 0.f;
    f32x4 acc = {0.f, 0.f, 0.f, 0.f};
    for (int s = 0; s < S; ++s) {
        size_t mi = ((size_t)s * NB * LSEQ + qg) * 2;
        float w = exp2f(mlg[mi] - M);   // empty/fully-masked splits -> w=0
        den += w * mlg[mi + 1];
        f16x4 ov = *(const f16x4*)(opart + (size_t)s * (NB * LSEQ * DIM) + base);
        acc[0] += w * (float)ov[0]; acc[1] += w * (float)ov[1];
        acc[2] += w * (float)ov[2]; acc[3] += w * (float)ov[3];
    }
    float inv = 1.0f / den;
    f32x4 res = {acc[0]*inv, acc[1]*inv, acc[2]*inv, acc[3]*inv};
    *(f32x4*)(outg + base) = res;
}

extern "C" void kernel_launch(void* const* d_in, const int* in_sizes, int n_in,
                              void* d_out, int out_size, void* d_ws, size_t ws_size,
                              hipStream_t stream) {
    const float* q  = (const float*)d_in[0];
    const float* k  = (const float*)d_in[1];
    const float* v  = (const float*)d_in[2];
    const int*   vl = (const int*)d_in[3];
    float* out = (float*)d_out;

    const size_t perm_b = (size_t)NB * LSEQ * sizeof(int);          // 128 KB
    const size_t kv_b   = (size_t)NB * LSEQ * DIM * sizeof(f16);    // 4 MB each
    auto need = [&](int S) {
        return perm_b + 2 * kv_b
             + (size_t)S * NB * LSEQ * 2 * sizeof(float)
             + (size_t)S * NB * LSEQ * DIM * sizeof(f16);
    };
    int S;
    if      (ws_size >= need(4)) S = 4;
    else if (ws_size >= need(2)) S = 2;
    else                         S = 1;

    int*   perm  = (int*)d_ws;
    f16*   k16   = (f16*)((char*)d_ws + perm_b);
    f16*   v16   = (f16*)((char*)d_ws + perm_b + kv_b);
    float* mlg   = (float*)((char*)d_ws + perm_b + 2 * kv_b);
    f16*   opart = (f16*)((char*)d_ws + perm_b + 2 * kv_b
                          + (size_t)S * NB * LSEQ * 2 * sizeof(float));

    prep<<<NB * NT + NB, 256, 0, stream>>>(k, v, vl, k16, v16, perm);

    attn_fwd<<<dim3(NQT * NB * S), dim3(256), 0, stream>>>(
        q, vl, k16, v16, out, perm, opart, mlg, S);

    if (S > 1) {
        const int mthreads = NB * LSEQ * DIM / 4;
        merge_k<<<dim3(mthreads / 256), dim3(256), 0, stream>>>(opart, mlg, out, S);
    }
}